// Round 4
// baseline (448.906 us; speedup 1.0000x reference)
//
#include <hip/hip_runtime.h>
#include <math.h>

// TopoBrainPhysical fused forward. Round 4: 2 lanes per batch element +
// full weight staging in LDS (~14.6KB). All hot-loop weight reads are
// ds_read_b128 at compile-time offsets (uniform address -> broadcast, no
// bank conflicts). Phase 1 (encoder/corners/mixing) redundant per lane-pair
// (wave-issue cost counted once per 32 elements); phase 2 (node MLP +
// readout-l1, the dominant FMA mass) split 4 grid cells per lane; t[24]
// pair-reduced with one DPP quad_perm butterfly. All register arrays
// statically indexed.

#define PI_F 3.14159265358979323846f

// ---- LDS layout (dword offsets; every b128-read block is 16B-aligned) ----
#define O_EW1   0      // [4][24]
#define O_EB1   96     // [24]
#define O_EW2   120    // [24][24]
#define O_EB2   696    // [24]
#define O_EW3T  720    // [3][24]  (transposed at stage time)
#define O_EB3   792    // [3] (pad 4)
#define O_NW1   796    // [4][24]
#define O_NB1   892    // [24]
#define O_NW2   916    // [24][12]
#define O_NB2   1204   // [12]
#define O_RW1   1216   // [96][24]
#define O_RB1   3520   // [24]
#define O_RW2   3544   // [24][4]
#define O_RB2   3640   // [4]
#define LDS_DW  3648

__device__ __forceinline__ float fast_tanh(float v) {
    float e = __expf(2.0f * v);
    return 1.0f - 2.0f * __builtin_amdgcn_rcpf(e + 1.0f);
}

// sum over lane pairs (lanes 2k, 2k+1); both lanes receive the sum.
__device__ __forceinline__ float pair_sum(float x) {
    x += __int_as_float(__builtin_amdgcn_update_dpp(
             0, __float_as_int(x), 0xB1, 0xF, 0xF, true)); // quad_perm {1,0,3,2}
    return x;
}

__device__ __forceinline__ float4 ldsv4(const float* w, int dwoff) {
    return *reinterpret_cast<const float4*>(w + dwoff);
}

extern "C" __global__ void __launch_bounds__(256, 4)
topo_fwd_kernel(const float* __restrict__ x,
                const float* __restrict__ ew1, const float* __restrict__ eb1,
                const float* __restrict__ ew2, const float* __restrict__ eb2,
                const float* __restrict__ ew3, const float* __restrict__ eb3,
                const float* __restrict__ nw1, const float* __restrict__ nb1,
                const float* __restrict__ nw2, const float* __restrict__ nb2,
                const float* __restrict__ alog, const float* __restrict__ rlog,
                const float* __restrict__ rw1, const float* __restrict__ rb1,
                const float* __restrict__ rw2, const float* __restrict__ rb2,
                float* __restrict__ out, int B)
{
    __shared__ float w[LDS_DW];

    // ---------------- stage weights into LDS (coalesced-ish, tiny) --------
    {
        const int t = threadIdx.x;
        for (int i = t; i < 96;  i += 256) w[O_EW1 + i] = ew1[i];
        for (int i = t; i < 24;  i += 256) w[O_EB1 + i] = eb1[i];
        for (int i = t; i < 576; i += 256) w[O_EW2 + i] = ew2[i];
        for (int i = t; i < 24;  i += 256) w[O_EB2 + i] = eb2[i];
        for (int i = t; i < 72;  i += 256) w[O_EW3T + (i % 3) * 24 + (i / 3)] = ew3[i];
        for (int i = t; i < 3;   i += 256) w[O_EB3 + i] = eb3[i];
        for (int i = t; i < 96;  i += 256) w[O_NW1 + i] = nw1[i];
        for (int i = t; i < 24;  i += 256) w[O_NB1 + i] = nb1[i];
        for (int i = t; i < 288; i += 256) w[O_NW2 + i] = nw2[i];
        for (int i = t; i < 12;  i += 256) w[O_NB2 + i] = nb2[i];
        for (int i = t; i < 2304;i += 256) w[O_RW1 + i] = rw1[i];
        for (int i = t; i < 24;  i += 256) w[O_RB1 + i] = rb1[i];
        for (int i = t; i < 96;  i += 256) w[O_RW2 + i] = rw2[i];
        for (int i = t; i < 4;   i += 256) w[O_RB2 + i] = rb2[i];
    }
    __syncthreads();

    const int tid  = blockIdx.x * blockDim.x + threadIdx.x;
    const int half = tid & 1;
    const int b    = tid >> 1;
    const int bc   = (b < B) ? b : (B - 1);   // clamp; no early return pre-sync

    // ---------------- normalized adjacency (wave-uniform, from global) ----
    float ang[4][4];
    {
        float m = fmaxf(fmaxf(alog[0], alog[1]), fmaxf(alog[2], alog[3]));
        float e0 = __expf(alog[0] - m), e1 = __expf(alog[1] - m);
        float e2 = __expf(alog[2] - m), e3 = __expf(alog[3] - m);
        float s = e0 + e1 + e2 + e3;
        float sm[4] = { e0 / s, e1 / s, e2 / s, e3 / s };
        #pragma unroll
        for (int i = 0; i < 4; ++i) {
            const int jn = (i + 3) & 3, jp = (i + 1) & 3;
            float inv = 1.0f / fmaxf(sm[jn] + sm[jp], 1e-6f);
            #pragma unroll
            for (int j = 0; j < 4; ++j) {
                float adj = (j == jn || j == jp) ? 1.0f : 0.0f;
                ang[i][j] = sm[j] * adj * inv;
            }
        }
    }
    float rad[2][2];
    {
        float m = fmaxf(rlog[0], rlog[1]);
        float f0 = __expf(rlog[0] - m), f1 = __expf(rlog[1] - m);
        float fs = f0 + f1;
        float sm0 = f0 / fs, sm1 = f1 / fs;
        rad[0][0] = 0.0f; rad[0][1] = sm1 / fmaxf(sm1, 1e-6f);
        rad[1][1] = 0.0f; rad[1][0] = sm0 / fmaxf(sm0, 1e-6f);
    }

    // ---------------- encoder (redundant per lane-pair) -------------------
    const float4 xv = *reinterpret_cast<const float4*>(x + (size_t)bc * 60 + 56);

    float zt[24];
    #pragma unroll
    for (int c = 0; c < 6; ++c) {
        float4 b4 = ldsv4(w, O_EB1 + c * 4);
        float4 w0 = ldsv4(w, O_EW1 + 0 * 24 + c * 4);
        float4 w1 = ldsv4(w, O_EW1 + 1 * 24 + c * 4);
        float4 w2 = ldsv4(w, O_EW1 + 2 * 24 + c * 4);
        float4 w3 = ldsv4(w, O_EW1 + 3 * 24 + c * 4);
        zt[c*4+0] = fast_tanh(b4.x + xv.x*w0.x + xv.y*w1.x + xv.z*w2.x + xv.w*w3.x);
        zt[c*4+1] = fast_tanh(b4.y + xv.x*w0.y + xv.y*w1.y + xv.z*w2.y + xv.w*w3.y);
        zt[c*4+2] = fast_tanh(b4.z + xv.x*w0.z + xv.y*w1.z + xv.z*w2.z + xv.w*w3.z);
        zt[c*4+3] = fast_tanh(b4.w + xv.x*w0.w + xv.y*w1.w + xv.z*w2.w + xv.w*w3.w);
    }

    float a2[24];
    #pragma unroll
    for (int c = 0; c < 6; ++c) {
        float4 b4 = ldsv4(w, O_EB2 + c * 4);
        a2[c*4+0] = b4.x; a2[c*4+1] = b4.y; a2[c*4+2] = b4.z; a2[c*4+3] = b4.w;
    }
    #pragma unroll
    for (int k = 0; k < 24; ++k) {
        const float zk = zt[k];
        #pragma unroll
        for (int c = 0; c < 6; ++c) {
            float4 wv = ldsv4(w, O_EW2 + k * 24 + c * 4);
            a2[c*4+0] += zk * wv.x; a2[c*4+1] += zk * wv.y;
            a2[c*4+2] += zk * wv.z; a2[c*4+3] += zk * wv.w;
        }
    }
    float zt2[24];
    #pragma unroll
    for (int j = 0; j < 24; ++j) zt2[j] = fast_tanh(a2[j]);

    float z0 = w[O_EB3 + 0], z1 = w[O_EB3 + 1], z2 = w[O_EB3 + 2];
    #pragma unroll
    for (int c = 0; c < 6; ++c) {
        float4 v0 = ldsv4(w, O_EW3T + 0 * 24 + c * 4);
        float4 v1 = ldsv4(w, O_EW3T + 1 * 24 + c * 4);
        float4 v2 = ldsv4(w, O_EW3T + 2 * 24 + c * 4);
        z0 += zt2[c*4+0]*v0.x + zt2[c*4+1]*v0.y + zt2[c*4+2]*v0.z + zt2[c*4+3]*v0.w;
        z1 += zt2[c*4+0]*v1.x + zt2[c*4+1]*v1.y + zt2[c*4+2]*v1.z + zt2[c*4+3]*v1.w;
        z2 += zt2[c*4+0]*v2.x + zt2[c*4+1]*v2.y + zt2[c*4+2]*v2.z + zt2[c*4+3]*v2.w;
    }

    // ---------------- bilinear corner weights ----------------
    const float r = 1.0f / (1.0f + __expf(-z0));
    const float p = (z1 + PI_F) / (2.0f * PI_F) * 4.0f;
    const float r0f = truncf(r), p0f = truncf(p);
    const float dr = r - r0f, dp = p - p0f;
    const int r0i = (int)r0f, p0i = (int)p0f;

    const float w0c = (1.0f - dr) * (1.0f - dp);
    const float w1c = (1.0f - dr) * dp;
    const float w2c = dr * (1.0f - dp);
    const float w3c = dr * dp;

    const int ri0 = min(r0i, 1);
    const int ri2 = min(r0i + 1, 1);
    const int pi0 = p0i & 3;
    const int pi1 = (p0i + 1) & 3;

    const int c0 = ri0 * 4 + pi0, c1 = ri0 * 4 + pi1;
    const int c2 = ri2 * 4 + pi0, c3 = ri2 * 4 + pi1;

    float cnt[8], wsum[8];
    #pragma unroll
    for (int n = 0; n < 8; ++n) {
        float cm = 0.0f, cw = 0.0f;
        if (c0 == n && w0c > 0.0f) { cm += 1.0f; cw += w0c; }
        if (c1 == n && w1c > 0.0f) { cm += 1.0f; cw += w1c; }
        if (c2 == n && w2c > 0.0f) { cm += 1.0f; cw += w2c; }
        if (c3 == n && w3c > 0.0f) { cm += 1.0f; cw += w3c; }
        cnt[n] = cm; wsum[n] = cw;
    }

    float mc[8], mw[8];
    #pragma unroll
    for (int n = 0; n < 8; ++n) {
        float ac = cnt[n], aw = wsum[n];
        #pragma unroll
        for (int j = 0; j < 4; ++j) {
            const float g = ang[n >> 1][j];
            ac += g * cnt[2 * j + (n & 1)];
            aw += g * wsum[2 * j + (n & 1)];
        }
        #pragma unroll
        for (int j = 0; j < 2; ++j) {
            const float g = rad[n >> 2][j];
            ac += g * cnt[4 * j + (n & 3)];
            aw += g * wsum[4 * j + (n & 3)];
        }
        mc[n] = ac; mw[n] = aw;
    }

    // this lane owns cells n = half*4 + cc, cc = 0..3
    float mcs[4], mws[4];
    #pragma unroll
    for (int cc = 0; cc < 4; ++cc) {
        mcs[cc] = half ? mc[cc + 4] : mc[cc];
        mws[cc] = half ? mw[cc + 4] : mw[cc];
    }

    // ---------------- node MLP + readout-l1 partial (4 cells/lane) --------
    float t[24];
    #pragma unroll
    for (int j = 0; j < 24; ++j) t[j] = 0.0f;

    // runtime (per-lane) rw1 base: half*4 cells, 12 rows x 24 dw per cell
    const int rbase0 = O_RW1 + half * 4 * 288;

    #pragma unroll
    for (int cc = 0; cc < 4; ++cc) {
        const float mc_ = mcs[cc], mw_ = mws[cc];
        const float f0 = mc_ * z0, f1 = mc_ * z1, f2 = mc_ * z2;

        float ho[12];
        #pragma unroll
        for (int c = 0; c < 3; ++c) {
            float4 b4 = ldsv4(w, O_NB2 + c * 4);
            ho[c*4+0] = b4.x; ho[c*4+1] = b4.y; ho[c*4+2] = b4.z; ho[c*4+3] = b4.w;
        }
        #pragma unroll
        for (int c = 0; c < 6; ++c) {
            float4 b1 = ldsv4(w, O_NB1 + c * 4);
            float4 u0 = ldsv4(w, O_NW1 + 0 * 24 + c * 4);
            float4 u1 = ldsv4(w, O_NW1 + 1 * 24 + c * 4);
            float4 u2 = ldsv4(w, O_NW1 + 2 * 24 + c * 4);
            float4 u3 = ldsv4(w, O_NW1 + 3 * 24 + c * 4);
            const float h0 = fast_tanh(b1.x + f0*u0.x + f1*u1.x + f2*u2.x + mw_*u3.x);
            const float h1 = fast_tanh(b1.y + f0*u0.y + f1*u1.y + f2*u2.y + mw_*u3.y);
            const float h2 = fast_tanh(b1.z + f0*u0.z + f1*u1.z + f2*u2.z + mw_*u3.z);
            const float h3 = fast_tanh(b1.w + f0*u0.w + f1*u1.w + f2*u2.w + mw_*u3.w);
            #pragma unroll
            for (int jj = 0; jj < 4; ++jj) {
                const float hj = (jj == 0) ? h0 : (jj == 1) ? h1 : (jj == 2) ? h2 : h3;
                const int row = O_NW2 + (c * 4 + jj) * 12;
                float4 n0 = ldsv4(w, row + 0);
                float4 n1 = ldsv4(w, row + 4);
                float4 n2 = ldsv4(w, row + 8);
                ho[0] += hj*n0.x; ho[1]  += hj*n0.y; ho[2]  += hj*n0.z; ho[3]  += hj*n0.w;
                ho[4] += hj*n1.x; ho[5]  += hj*n1.y; ho[6]  += hj*n1.z; ho[7]  += hj*n1.w;
                ho[8] += hj*n2.x; ho[9]  += hj*n2.y; ho[10] += hj*n2.z; ho[11] += hj*n2.w;
            }
        }
        // t += ho . rw1[cell rows]
        #pragma unroll
        for (int d = 0; d < 12; ++d) {
            const float hd = ho[d];
            #pragma unroll
            for (int c = 0; c < 6; ++c) {
                float4 rv = ldsv4(w, rbase0 + cc * 288 + d * 24 + c * 4);
                t[c*4+0] += hd * rv.x; t[c*4+1] += hd * rv.y;
                t[c*4+2] += hd * rv.z; t[c*4+3] += hd * rv.w;
            }
        }
    }

    // pair-reduce t; add rb1
    #pragma unroll
    for (int j = 0; j < 24; ++j) t[j] = pair_sum(t[j]) + w[O_RB1 + j];

    // ---------------- readout layer 2 (redundant; even lane stores) -------
    float4 ob = ldsv4(w, O_RB2);
    float o0 = ob.x, o1 = ob.y, o2 = ob.z, o3 = ob.w;
    #pragma unroll
    for (int j = 0; j < 24; ++j) {
        const float tt = fast_tanh(t[j]);
        float4 rv = ldsv4(w, O_RW2 + j * 4);
        o0 += tt * rv.x; o1 += tt * rv.y; o2 += tt * rv.z; o3 += tt * rv.w;
    }
    if (half == 0 && b < B) {
        float4 ov; ov.x = o0; ov.y = o1; ov.z = o2; ov.w = o3;
        *reinterpret_cast<float4*>(out + (size_t)b * 4) = ov;
    }
}

extern "C" void kernel_launch(void* const* d_in, const int* in_sizes, int n_in,
                              void* d_out, int out_size, void* d_ws, size_t ws_size,
                              hipStream_t stream) {
    const float* x    = (const float*)d_in[0];
    const float* ew1  = (const float*)d_in[1];
    const float* eb1  = (const float*)d_in[2];
    const float* ew2  = (const float*)d_in[3];
    const float* eb2  = (const float*)d_in[4];
    const float* ew3  = (const float*)d_in[5];
    const float* eb3  = (const float*)d_in[6];
    const float* nw1  = (const float*)d_in[7];
    const float* nb1  = (const float*)d_in[8];
    const float* nw2  = (const float*)d_in[9];
    const float* nb2  = (const float*)d_in[10];
    const float* alog = (const float*)d_in[11];
    const float* rlog = (const float*)d_in[12];
    const float* rw1  = (const float*)d_in[13];
    const float* rb1  = (const float*)d_in[14];
    const float* rw2  = (const float*)d_in[15];
    const float* rb2  = (const float*)d_in[16];
    float* out = (float*)d_out;

    const int B = in_sizes[0] / 60;   // x is (B, 15, 4)
    const long long total = (long long)B * 2;
    const int block = 256;
    const int grid = (int)((total + block - 1) / block);
    topo_fwd_kernel<<<grid, block, 0, stream>>>(
        x, ew1, eb1, ew2, eb2, ew3, eb3, nw1, nb1, nw2, nb2,
        alog, rlog, rw1, rb1, rw2, rb2, out, B);
}

// Round 5
// 111.503 us; speedup vs baseline: 4.0260x; 4.0260x over previous
//
#include <hip/hip_runtime.h>
#include <math.h>

// TopoBrainPhysical fused forward, round 5.
// 2 lanes per batch element (262144 threads -> 4096 waves -> 4 waves/SIMD).
// Phase 1 (encoder + corners + adjacency mixing): redundant per lane pair,
//   R2-style global scalar weight indexing (known-good codegen: s_load +
//   SGPR-operand FMA, ~60 VGPR).
// Phase 2 (node MLP + readout-l1, ~75% of FMAs): 4 grid cells per lane,
//   weights from an 11.4KB LDS copy via ds_read_b128 at compile-time offsets
//   (uniform address -> broadcast). t[24] pair-reduced with one DPP.
// Spill control (R4 post-mortem: 1.4GB scratch traffic from hoisted float4
// temps at a 64-VGPR allocator target):
//   - amdgpu_waves_per_eu(4,4) pins the register budget at 128 VGPRs
//   - sched_barrier(0) after each cell stops cross-cell ds_read mass-hoisting
//   - live set ~70 regs; all register arrays statically indexed (rule #20).

#define PI_F 3.14159265358979323846f

// ---- LDS float4 layout (dword offsets /4 = float4 indices) ----
// NW1 [4][24]  dw 0     q 0..23    (rows e=0..3 of node_w1; rows 4..11 unused)
// NB1 [24]     dw 96    q 24..29
// NW2 [24][12] dw 120   q 30..101
// NB2 [12]     dw 408   q 102..104
// RW1 [96][24] dw 420   q 105..680
// RB1 [24]     dw 2724  (scalar reads)
// RW2 [24][4]  dw 2748  q 687..710
// RB2 [4]      dw 2844  q 711
#define LDS_Q 712

__device__ __forceinline__ float fast_tanh(float v) {
    // tanh(v) = 1 - 2/(e^{2v}+1); saturates correctly at +/-inf.
    float e = __expf(2.0f * v);
    return 1.0f - 2.0f * __builtin_amdgcn_rcpf(e + 1.0f);
}

// sum over lane pairs (2k, 2k+1); both lanes receive the sum.
__device__ __forceinline__ float pair_sum(float x) {
    x += __int_as_float(__builtin_amdgcn_update_dpp(
             0, __float_as_int(x), 0xB1, 0xF, 0xF, true)); // quad_perm {1,0,3,2}
    return x;
}

extern "C" __global__
__attribute__((amdgpu_flat_work_group_size(256, 256)))
__attribute__((amdgpu_waves_per_eu(4, 4)))
void topo_fwd_kernel(const float* __restrict__ x,
                const float* __restrict__ ew1, const float* __restrict__ eb1,
                const float* __restrict__ ew2, const float* __restrict__ eb2,
                const float* __restrict__ ew3, const float* __restrict__ eb3,
                const float* __restrict__ nw1, const float* __restrict__ nb1,
                const float* __restrict__ nw2, const float* __restrict__ nb2,
                const float* __restrict__ alog, const float* __restrict__ rlog,
                const float* __restrict__ rw1, const float* __restrict__ rb1,
                const float* __restrict__ rw2, const float* __restrict__ rb2,
                float* __restrict__ out, int B)
{
    __shared__ float4 wq[LDS_Q];
    float* wf = reinterpret_cast<float*>(wq);

    // ---------------- stage phase-2 weights into LDS ----------------------
    {
        const int tt = threadIdx.x;
        for (int i = tt; i < 96;   i += 256) wf[i]        = nw1[i];
        for (int i = tt; i < 24;   i += 256) wf[96 + i]   = nb1[i];
        for (int i = tt; i < 288;  i += 256) wf[120 + i]  = nw2[i];
        for (int i = tt; i < 12;   i += 256) wf[408 + i]  = nb2[i];
        for (int i = tt; i < 2304; i += 256) wf[420 + i]  = rw1[i];
        for (int i = tt; i < 24;   i += 256) wf[2724 + i] = rb1[i];
        for (int i = tt; i < 96;   i += 256) wf[2748 + i] = rw2[i];
        for (int i = tt; i < 4;    i += 256) wf[2844 + i] = rb2[i];
    }
    __syncthreads();

    const int tid  = blockIdx.x * blockDim.x + threadIdx.x;
    const int half = tid & 1;
    const int b    = tid >> 1;
    if (b >= B) return;   // grid is exact for B=131072; kept for safety

    // ---------------- normalized adjacency (wave-uniform) ----------------
    float ang[4][4];
    {
        float m = fmaxf(fmaxf(alog[0], alog[1]), fmaxf(alog[2], alog[3]));
        float e0 = __expf(alog[0] - m), e1 = __expf(alog[1] - m);
        float e2 = __expf(alog[2] - m), e3 = __expf(alog[3] - m);
        float s = e0 + e1 + e2 + e3;
        float sm[4] = { e0 / s, e1 / s, e2 / s, e3 / s };
        #pragma unroll
        for (int i = 0; i < 4; ++i) {
            const int jn = (i + 3) & 3, jp = (i + 1) & 3;
            float inv = 1.0f / fmaxf(sm[jn] + sm[jp], 1e-6f);
            #pragma unroll
            for (int j = 0; j < 4; ++j) {
                float adj = (j == jn || j == jp) ? 1.0f : 0.0f;
                ang[i][j] = sm[j] * adj * inv;
            }
        }
    }
    float rad[2][2];
    {
        float m = fmaxf(rlog[0], rlog[1]);
        float f0 = __expf(rlog[0] - m), f1 = __expf(rlog[1] - m);
        float fs = f0 + f1;
        float sm0 = f0 / fs, sm1 = f1 / fs;
        rad[0][0] = 0.0f; rad[0][1] = sm1 / fmaxf(sm1, 1e-6f);
        rad[1][1] = 0.0f; rad[1][0] = sm0 / fmaxf(sm0, 1e-6f);
    }

    // ---------------- encoder (redundant per lane pair; global weights) ---
    const float4 xv = *reinterpret_cast<const float4*>(x + (size_t)b * 60 + 56);

    float zt[24];
    #pragma unroll
    for (int j = 0; j < 24; ++j) {
        float a = eb1[j];
        a += xv.x * ew1[j];
        a += xv.y * ew1[24 + j];
        a += xv.z * ew1[48 + j];
        a += xv.w * ew1[72 + j];
        zt[j] = fast_tanh(a);
    }
    float zt2[24];
    #pragma unroll
    for (int j = 0; j < 24; ++j) {
        float a = eb2[j];
        #pragma unroll
        for (int k = 0; k < 24; ++k) a += zt[k] * ew2[k * 24 + j];
        zt2[j] = fast_tanh(a);
    }
    float z0 = eb3[0], z1 = eb3[1], z2 = eb3[2];
    #pragma unroll
    for (int k = 0; k < 24; ++k) {
        z0 += zt2[k] * ew3[k * 3 + 0];
        z1 += zt2[k] * ew3[k * 3 + 1];
        z2 += zt2[k] * ew3[k * 3 + 2];
    }

    // ---------------- bilinear corner weights ----------------
    const float r = 1.0f / (1.0f + __expf(-z0));      // * (R-1)=1
    const float p = (z1 + PI_F) / (2.0f * PI_F) * 4.0f;
    const float r0f = truncf(r), p0f = truncf(p);
    const float dr = r - r0f, dp = p - p0f;
    const int r0i = (int)r0f, p0i = (int)p0f;

    const float w0c = (1.0f - dr) * (1.0f - dp);
    const float w1c = (1.0f - dr) * dp;
    const float w2c = dr * (1.0f - dp);
    const float w3c = dr * dp;

    const int ri0 = min(r0i, 1);
    const int ri2 = min(r0i + 1, 1);
    const int pi0 = p0i & 3;          // floored mod 4 (works for negatives)
    const int pi1 = (p0i + 1) & 3;

    const int c0 = ri0 * 4 + pi0, c1 = ri0 * 4 + pi1;
    const int c2 = ri2 * 4 + pi0, c3 = ri2 * 4 + pi1;

    float cnt[8], wsum[8];
    #pragma unroll
    for (int n = 0; n < 8; ++n) {
        float cm = 0.0f, cw = 0.0f;
        if (c0 == n && w0c > 0.0f) { cm += 1.0f; cw += w0c; }
        if (c1 == n && w1c > 0.0f) { cm += 1.0f; cw += w1c; }
        if (c2 == n && w2c > 0.0f) { cm += 1.0f; cw += w2c; }
        if (c3 == n && w3c > 0.0f) { cm += 1.0f; cw += w3c; }
        cnt[n] = cm; wsum[n] = cw;
    }

    // h + h_ang + h_rad (faithful .view() layout mixing), 2 channels only
    float mc[8], mw[8];
    #pragma unroll
    for (int n = 0; n < 8; ++n) {
        float ac = cnt[n], aw = wsum[n];
        #pragma unroll
        for (int j = 0; j < 4; ++j) {
            const float g = ang[n >> 1][j];
            ac += g * cnt[2 * j + (n & 1)];
            aw += g * wsum[2 * j + (n & 1)];
        }
        #pragma unroll
        for (int j = 0; j < 2; ++j) {
            const float g = rad[n >> 2][j];
            ac += g * cnt[4 * j + (n & 3)];
            aw += g * wsum[4 * j + (n & 3)];
        }
        mc[n] = ac; mw[n] = aw;
    }

    // this lane owns cells n = half*4 + cc, cc = 0..3
    float mcs[4], mws[4];
    #pragma unroll
    for (int cc = 0; cc < 4; ++cc) {
        mcs[cc] = half ? mc[cc + 4] : mc[cc];
        mws[cc] = half ? mw[cc + 4] : mw[cc];
    }

    __builtin_amdgcn_sched_barrier(0);   // fence: keep phase-1/phase-2 apart

    // ---------------- phase 2: node MLP + readout-l1 (LDS weights) --------
    float t[24];
    #pragma unroll
    for (int j = 0; j < 24; ++j) t[j] = 0.0f;

    const int rqb = 105 + half * 288;    // float4 base of this lane's 4 cells

    #pragma unroll
    for (int cc = 0; cc < 4; ++cc) {
        const float mc_ = mcs[cc], mw_ = mws[cc];
        const float f0 = mc_ * z0, f1 = mc_ * z1, f2 = mc_ * z2;

        float ho[12];
        {
            float4 bA = wq[102], bB = wq[103], bC = wq[104];
            ho[0] = bA.x; ho[1]  = bA.y; ho[2]  = bA.z; ho[3]  = bA.w;
            ho[4] = bB.x; ho[5]  = bB.y; ho[6]  = bB.z; ho[7]  = bB.w;
            ho[8] = bC.x; ho[9]  = bC.y; ho[10] = bC.z; ho[11] = bC.w;
        }
        #pragma unroll
        for (int c = 0; c < 6; ++c) {
            float4 b1 = wq[24 + c];
            float4 u0 = wq[c],      u1 = wq[6 + c];
            float4 u2 = wq[12 + c], u3 = wq[18 + c];
            float h[4];
            h[0] = fast_tanh(b1.x + f0*u0.x + f1*u1.x + f2*u2.x + mw_*u3.x);
            h[1] = fast_tanh(b1.y + f0*u0.y + f1*u1.y + f2*u2.y + mw_*u3.y);
            h[2] = fast_tanh(b1.z + f0*u0.z + f1*u1.z + f2*u2.z + mw_*u3.z);
            h[3] = fast_tanh(b1.w + f0*u0.w + f1*u1.w + f2*u2.w + mw_*u3.w);
            #pragma unroll
            for (int jj = 0; jj < 4; ++jj) {
                const int j = c * 4 + jj;
                const float hj = h[jj];
                float4 n0 = wq[30 + j * 3], n1 = wq[31 + j * 3], n2 = wq[32 + j * 3];
                ho[0] += hj*n0.x; ho[1]  += hj*n0.y; ho[2]  += hj*n0.z; ho[3]  += hj*n0.w;
                ho[4] += hj*n1.x; ho[5]  += hj*n1.y; ho[6]  += hj*n1.z; ho[7]  += hj*n1.w;
                ho[8] += hj*n2.x; ho[9]  += hj*n2.y; ho[10] += hj*n2.z; ho[11] += hj*n2.w;
            }
        }
        #pragma unroll
        for (int d = 0; d < 12; ++d) {
            const float hd = ho[d];
            const int rb = rqb + cc * 72 + d * 6;
            #pragma unroll
            for (int c = 0; c < 6; ++c) {
                float4 rv = wq[rb + c];
                t[c*4+0] += hd * rv.x; t[c*4+1] += hd * rv.y;
                t[c*4+2] += hd * rv.z; t[c*4+3] += hd * rv.w;
            }
        }
        __builtin_amdgcn_sched_barrier(0);  // stop cross-cell ds_read hoisting
    }

    // pair-reduce t; add rb1
    #pragma unroll
    for (int j = 0; j < 24; ++j) t[j] = pair_sum(t[j]) + wf[2724 + j];

    // ---------------- readout layer 2 (redundant; even lane stores) -------
    float4 ob = wq[711];
    float o0 = ob.x, o1 = ob.y, o2 = ob.z, o3 = ob.w;
    #pragma unroll
    for (int j = 0; j < 24; ++j) {
        const float tv = fast_tanh(t[j]);
        float4 rv = wq[687 + j];
        o0 += tv * rv.x; o1 += tv * rv.y; o2 += tv * rv.z; o3 += tv * rv.w;
    }
    if (half == 0) {
        float4 ov; ov.x = o0; ov.y = o1; ov.z = o2; ov.w = o3;
        *reinterpret_cast<float4*>(out + (size_t)b * 4) = ov;
    }
}

extern "C" void kernel_launch(void* const* d_in, const int* in_sizes, int n_in,
                              void* d_out, int out_size, void* d_ws, size_t ws_size,
                              hipStream_t stream) {
    const float* x    = (const float*)d_in[0];
    const float* ew1  = (const float*)d_in[1];
    const float* eb1  = (const float*)d_in[2];
    const float* ew2  = (const float*)d_in[3];
    const float* eb2  = (const float*)d_in[4];
    const float* ew3  = (const float*)d_in[5];
    const float* eb3  = (const float*)d_in[6];
    const float* nw1  = (const float*)d_in[7];
    const float* nb1  = (const float*)d_in[8];
    const float* nw2  = (const float*)d_in[9];
    const float* nb2  = (const float*)d_in[10];
    const float* alog = (const float*)d_in[11];
    const float* rlog = (const float*)d_in[12];
    const float* rw1  = (const float*)d_in[13];
    const float* rb1  = (const float*)d_in[14];
    const float* rw2  = (const float*)d_in[15];
    const float* rb2  = (const float*)d_in[16];
    float* out = (float*)d_out;

    const int B = in_sizes[0] / 60;   // x is (B, 15, 4)
    const long long total = (long long)B * 2;
    const int block = 256;
    const int grid = (int)((total + block - 1) / block);
    topo_fwd_kernel<<<grid, block, 0, stream>>>(
        x, ew1, eb1, ew2, eb2, ew3, eb3, nw1, nb1, nw2, nb2,
        alog, rlog, rw1, rb1, rw2, rb2, out, B);
}

// Round 6
// 50.271 us; speedup vs baseline: 8.9297x; 2.2180x over previous
//
#include <hip/hip_runtime.h>
#include <math.h>

// TopoBrainPhysical fused forward, round 6: TWO-KERNEL SPLIT.
// K1 (encoder+corners+mixing): 1 thread/elem, no redundancy, small live set,
//     writes z,mc[8],mw[8] (20 floats) per element to d_ws.
// K2 (node MLP + readout, ~80% of FMAs): 4 lanes/elem, 2 cells/lane (exact
//     split, zero redundancy), 8192 waves (6+ waves/SIMD), weights in 11.6KB
//     LDS (rw1 cell stride padded 288->296 floats to break bank aliasing),
//     t[24] quad-reduced via DPP.
// All register arrays statically indexed. Fallback fused kernel if ws small.

#define PI_F 3.14159265358979323846f

__device__ __forceinline__ float fast_tanh(float v) {
    float e = __expf(2.0f * v);
    return 1.0f - 2.0f * __builtin_amdgcn_rcpf(e + 1.0f);
}

__device__ __forceinline__ float quad_sum(float x) {
    x += __int_as_float(__builtin_amdgcn_update_dpp(
             0, __float_as_int(x), 0xB1, 0xF, 0xF, true)); // {1,0,3,2}
    x += __int_as_float(__builtin_amdgcn_update_dpp(
             0, __float_as_int(x), 0x4E, 0xF, 0xF, true)); // {2,3,0,1}
    return x;
}

// ---------------- phase 1: encoder + corners + adjacency mixing -----------
__device__ __forceinline__ void phase1(
    int b,
    const float* __restrict__ x,
    const float* __restrict__ ew1, const float* __restrict__ eb1,
    const float* __restrict__ ew2, const float* __restrict__ eb2,
    const float* __restrict__ ew3, const float* __restrict__ eb3,
    const float* __restrict__ alog, const float* __restrict__ rlog,
    float& z0o, float& z1o, float& z2o, float (&mc)[8], float (&mw)[8])
{
    float ang[4][4];
    {
        float m = fmaxf(fmaxf(alog[0], alog[1]), fmaxf(alog[2], alog[3]));
        float e0 = __expf(alog[0] - m), e1 = __expf(alog[1] - m);
        float e2 = __expf(alog[2] - m), e3 = __expf(alog[3] - m);
        float s = e0 + e1 + e2 + e3;
        float sm[4] = { e0 / s, e1 / s, e2 / s, e3 / s };
        #pragma unroll
        for (int i = 0; i < 4; ++i) {
            const int jn = (i + 3) & 3, jp = (i + 1) & 3;
            float inv = 1.0f / fmaxf(sm[jn] + sm[jp], 1e-6f);
            #pragma unroll
            for (int j = 0; j < 4; ++j) {
                float adj = (j == jn || j == jp) ? 1.0f : 0.0f;
                ang[i][j] = sm[j] * adj * inv;
            }
        }
    }
    float rad[2][2];
    {
        float m = fmaxf(rlog[0], rlog[1]);
        float f0 = __expf(rlog[0] - m), f1 = __expf(rlog[1] - m);
        float fs = f0 + f1;
        float sm0 = f0 / fs, sm1 = f1 / fs;
        rad[0][0] = 0.0f; rad[0][1] = sm1 / fmaxf(sm1, 1e-6f);
        rad[1][1] = 0.0f; rad[1][0] = sm0 / fmaxf(sm0, 1e-6f);
    }

    const float4 xv = *reinterpret_cast<const float4*>(x + (size_t)b * 60 + 56);

    float zt[24];
    #pragma unroll
    for (int j = 0; j < 24; ++j) {
        float a = eb1[j];
        a += xv.x * ew1[j];
        a += xv.y * ew1[24 + j];
        a += xv.z * ew1[48 + j];
        a += xv.w * ew1[72 + j];
        zt[j] = fast_tanh(a);
    }
    float z0 = eb3[0], z1 = eb3[1], z2 = eb3[2];
    #pragma unroll
    for (int j = 0; j < 24; ++j) {
        float a = eb2[j];
        #pragma unroll
        for (int k = 0; k < 24; ++k) a += zt[k] * ew2[k * 24 + j];
        const float z2t = fast_tanh(a);
        z0 += z2t * ew3[j * 3 + 0];
        z1 += z2t * ew3[j * 3 + 1];
        z2 += z2t * ew3[j * 3 + 2];
    }

    const float r = 1.0f / (1.0f + __expf(-z0));
    const float p = (z1 + PI_F) / (2.0f * PI_F) * 4.0f;
    const float r0f = truncf(r), p0f = truncf(p);
    const float dr = r - r0f, dp = p - p0f;
    const int r0i = (int)r0f, p0i = (int)p0f;

    const float w0c = (1.0f - dr) * (1.0f - dp);
    const float w1c = (1.0f - dr) * dp;
    const float w2c = dr * (1.0f - dp);
    const float w3c = dr * dp;

    const int ri0 = min(r0i, 1);
    const int ri2 = min(r0i + 1, 1);
    const int pi0 = p0i & 3;
    const int pi1 = (p0i + 1) & 3;

    const int c0 = ri0 * 4 + pi0, c1 = ri0 * 4 + pi1;
    const int c2 = ri2 * 4 + pi0, c3 = ri2 * 4 + pi1;

    float cnt[8], wsum[8];
    #pragma unroll
    for (int n = 0; n < 8; ++n) {
        float cm = 0.0f, cw = 0.0f;
        if (c0 == n && w0c > 0.0f) { cm += 1.0f; cw += w0c; }
        if (c1 == n && w1c > 0.0f) { cm += 1.0f; cw += w1c; }
        if (c2 == n && w2c > 0.0f) { cm += 1.0f; cw += w2c; }
        if (c3 == n && w3c > 0.0f) { cm += 1.0f; cw += w3c; }
        cnt[n] = cm; wsum[n] = cw;
    }
    #pragma unroll
    for (int n = 0; n < 8; ++n) {
        float ac = cnt[n], aw = wsum[n];
        #pragma unroll
        for (int j = 0; j < 4; ++j) {
            const float g = ang[n >> 1][j];
            ac += g * cnt[2 * j + (n & 1)];
            aw += g * wsum[2 * j + (n & 1)];
        }
        #pragma unroll
        for (int j = 0; j < 2; ++j) {
            const float g = rad[n >> 2][j];
            ac += g * cnt[4 * j + (n & 3)];
            aw += g * wsum[4 * j + (n & 3)];
        }
        mc[n] = ac; mw[n] = aw;
    }
    z0o = z0; z1o = z1; z2o = z2;
}

// ---------------- kernel 1 ----------------
extern "C" __global__ void __launch_bounds__(256, 2)
topo_k1(const float* __restrict__ x,
        const float* __restrict__ ew1, const float* __restrict__ eb1,
        const float* __restrict__ ew2, const float* __restrict__ eb2,
        const float* __restrict__ ew3, const float* __restrict__ eb3,
        const float* __restrict__ alog, const float* __restrict__ rlog,
        float* __restrict__ ws, int B)
{
    const int b = blockIdx.x * blockDim.x + threadIdx.x;
    if (b >= B) return;

    float z0, z1, z2, mc[8], mw[8];
    phase1(b, x, ew1, eb1, ew2, eb2, ew3, eb3, alog, rlog, z0, z1, z2, mc, mw);

    float* wp = ws + (size_t)b * 20;
    float4 v0; v0.x = z0; v0.y = z1; v0.z = z2; v0.w = 0.0f;
    float4 v1; v1.x = mc[0]; v1.y = mc[1]; v1.z = mc[2]; v1.w = mc[3];
    float4 v2; v2.x = mc[4]; v2.y = mc[5]; v2.z = mc[6]; v2.w = mc[7];
    float4 v3; v3.x = mw[0]; v3.y = mw[1]; v3.z = mw[2]; v3.w = mw[3];
    float4 v4; v4.x = mw[4]; v4.y = mw[5]; v4.z = mw[6]; v4.w = mw[7];
    reinterpret_cast<float4*>(wp)[0] = v0;
    reinterpret_cast<float4*>(wp)[1] = v1;
    reinterpret_cast<float4*>(wp)[2] = v2;
    reinterpret_cast<float4*>(wp)[3] = v3;
    reinterpret_cast<float4*>(wp)[4] = v4;
}

// ---------------- kernel 2: LDS float layout ----------------
// NW1[4][24]@0  NB1[24]@96  NW2[24][12]@120  NB2[12]@408
// RW1 8 cells x (12x24) padded stride 296 @420   RB1[24]@2788
// RW2[24][4]@2812  RB2[4]@2908   total 2912 floats = 11648 B
#define K2_LDS 2912

extern "C" __global__ void __launch_bounds__(256, 6)
topo_k2(const float* __restrict__ ws,
        const float* __restrict__ nw1, const float* __restrict__ nb1,
        const float* __restrict__ nw2, const float* __restrict__ nb2,
        const float* __restrict__ rw1, const float* __restrict__ rb1,
        const float* __restrict__ rw2, const float* __restrict__ rb2,
        float* __restrict__ out, int B)
{
    __shared__ float wf[K2_LDS];
    const float4* wq = reinterpret_cast<const float4*>(wf);

    {
        const int tt = threadIdx.x;
        for (int i = tt; i < 96;   i += 256) wf[i]        = nw1[i];
        for (int i = tt; i < 24;   i += 256) wf[96 + i]   = nb1[i];
        for (int i = tt; i < 288;  i += 256) wf[120 + i]  = nw2[i];
        for (int i = tt; i < 12;   i += 256) wf[408 + i]  = nb2[i];
        for (int i = tt; i < 2304; i += 256) {
            const int cell = i / 288, rem = i - cell * 288;
            wf[420 + cell * 296 + rem] = rw1[i];
        }
        for (int i = tt; i < 24;   i += 256) wf[2788 + i] = rb1[i];
        for (int i = tt; i < 96;   i += 256) wf[2812 + i] = rw2[i];
        for (int i = tt; i < 4;    i += 256) wf[2908 + i] = rb2[i];
    }
    __syncthreads();

    const int tid  = blockIdx.x * blockDim.x + threadIdx.x;
    const int lane = tid & 3;           // owns cells 2*lane, 2*lane+1
    const int b    = tid >> 2;
    if (b >= B) return;

    // per-element state from ws
    const float* wp = ws + (size_t)b * 20;
    const float4 zv = *reinterpret_cast<const float4*>(wp);
    const float2 mc2 = *reinterpret_cast<const float2*>(wp + 4 + 2 * lane);
    const float2 mw2 = *reinterpret_cast<const float2*>(wp + 12 + 2 * lane);
    const float z0 = zv.x, z1 = zv.y, z2 = zv.z;

    float t[24];
    #pragma unroll
    for (int j = 0; j < 24; ++j) t[j] = 0.0f;

    #pragma unroll
    for (int cc = 0; cc < 2; ++cc) {
        const float mc_ = cc ? mc2.y : mc2.x;
        const float mw_ = cc ? mw2.y : mw2.x;
        const float f0 = mc_ * z0, f1 = mc_ * z1, f2 = mc_ * z2;

        float ho[12];
        {
            float4 bA = wq[102], bB = wq[103], bC = wq[104];
            ho[0] = bA.x; ho[1]  = bA.y; ho[2]  = bA.z; ho[3]  = bA.w;
            ho[4] = bB.x; ho[5]  = bB.y; ho[6]  = bB.z; ho[7]  = bB.w;
            ho[8] = bC.x; ho[9]  = bC.y; ho[10] = bC.z; ho[11] = bC.w;
        }
        #pragma unroll
        for (int c = 0; c < 6; ++c) {
            float4 b1 = wq[24 + c];
            float4 u0 = wq[c],      u1 = wq[6 + c];
            float4 u2 = wq[12 + c], u3 = wq[18 + c];
            float h[4];
            h[0] = fast_tanh(b1.x + f0*u0.x + f1*u1.x + f2*u2.x + mw_*u3.x);
            h[1] = fast_tanh(b1.y + f0*u0.y + f1*u1.y + f2*u2.y + mw_*u3.y);
            h[2] = fast_tanh(b1.z + f0*u0.z + f1*u1.z + f2*u2.z + mw_*u3.z);
            h[3] = fast_tanh(b1.w + f0*u0.w + f1*u1.w + f2*u2.w + mw_*u3.w);
            #pragma unroll
            for (int jj = 0; jj < 4; ++jj) {
                const int j = c * 4 + jj;
                const float hj = h[jj];
                float4 n0 = wq[30 + j * 3], n1 = wq[31 + j * 3], n2 = wq[32 + j * 3];
                ho[0] += hj*n0.x; ho[1]  += hj*n0.y; ho[2]  += hj*n0.z; ho[3]  += hj*n0.w;
                ho[4] += hj*n1.x; ho[5]  += hj*n1.y; ho[6]  += hj*n1.z; ho[7]  += hj*n1.w;
                ho[8] += hj*n2.x; ho[9]  += hj*n2.y; ho[10] += hj*n2.z; ho[11] += hj*n2.w;
            }
        }
        // t += ho . rw1[cell]; cell = 2*lane+cc, padded stride 296 floats
        const int cellbase = 420 + (2 * lane + cc) * 296;   // dword offset
        #pragma unroll
        for (int d = 0; d < 12; ++d) {
            const float hd = ho[d];
            const int qb = (cellbase >> 2) + d * 6;          // float4 index
            #pragma unroll
            for (int c = 0; c < 6; ++c) {
                float4 rv = wq[qb + c];
                t[c*4+0] += hd * rv.x; t[c*4+1] += hd * rv.y;
                t[c*4+2] += hd * rv.z; t[c*4+3] += hd * rv.w;
            }
        }
        __builtin_amdgcn_sched_barrier(0);
    }

    // reduce across the 4 lanes (8 cells), add rb1
    #pragma unroll
    for (int j = 0; j < 24; ++j) t[j] = quad_sum(t[j]) + wf[2788 + j];

    // readout layer 2 (redundant in quad; lane 0 stores)
    float4 ob = wq[727];
    float o0 = ob.x, o1 = ob.y, o2 = ob.z, o3 = ob.w;
    #pragma unroll
    for (int j = 0; j < 24; ++j) {
        const float tv = fast_tanh(t[j]);
        float4 rv = wq[703 + j];
        o0 += tv * rv.x; o1 += tv * rv.y; o2 += tv * rv.z; o3 += tv * rv.w;
    }
    if (lane == 0) {
        float4 ov; ov.x = o0; ov.y = o1; ov.z = o2; ov.w = o3;
        *reinterpret_cast<float4*>(out + (size_t)b * 4) = ov;
    }
}

// ---------------- fallback fused kernel (if ws too small) ----------------
extern "C" __global__ void __launch_bounds__(256, 2)
topo_fused(const float* __restrict__ x,
           const float* __restrict__ ew1, const float* __restrict__ eb1,
           const float* __restrict__ ew2, const float* __restrict__ eb2,
           const float* __restrict__ ew3, const float* __restrict__ eb3,
           const float* __restrict__ nw1, const float* __restrict__ nb1,
           const float* __restrict__ nw2, const float* __restrict__ nb2,
           const float* __restrict__ alog, const float* __restrict__ rlog,
           const float* __restrict__ rw1, const float* __restrict__ rb1,
           const float* __restrict__ rw2, const float* __restrict__ rb2,
           float* __restrict__ out, int B)
{
    const int b = blockIdx.x * blockDim.x + threadIdx.x;
    if (b >= B) return;

    float z0, z1, z2, mc[8], mw[8];
    phase1(b, x, ew1, eb1, ew2, eb2, ew3, eb3, alog, rlog, z0, z1, z2, mc, mw);

    float t[24];
    #pragma unroll
    for (int j = 0; j < 24; ++j) t[j] = rb1[j];

    #pragma unroll
    for (int n = 0; n < 8; ++n) {
        const float f0 = mc[n] * z0, f1 = mc[n] * z1, f2 = mc[n] * z2;
        float ho[12];
        #pragma unroll
        for (int d = 0; d < 12; ++d) ho[d] = nb2[d];
        #pragma unroll
        for (int j = 0; j < 24; ++j) {
            const float hj = fast_tanh(nb1[j] + f0 * nw1[j] + f1 * nw1[24 + j]
                                       + f2 * nw1[48 + j] + mw[n] * nw1[72 + j]);
            #pragma unroll
            for (int d = 0; d < 12; ++d) ho[d] += hj * nw2[j * 12 + d];
        }
        #pragma unroll
        for (int d = 0; d < 12; ++d) {
            const int rbase = (n * 12 + d) * 24;
            #pragma unroll
            for (int j2 = 0; j2 < 24; ++j2) t[j2] += ho[d] * rw1[rbase + j2];
        }
    }

    float o0 = rb2[0], o1 = rb2[1], o2 = rb2[2], o3 = rb2[3];
    #pragma unroll
    for (int j = 0; j < 24; ++j) {
        const float tt = fast_tanh(t[j]);
        o0 += tt * rw2[j * 4 + 0];
        o1 += tt * rw2[j * 4 + 1];
        o2 += tt * rw2[j * 4 + 2];
        o3 += tt * rw2[j * 4 + 3];
    }
    float4 ov; ov.x = o0; ov.y = o1; ov.z = o2; ov.w = o3;
    *reinterpret_cast<float4*>(out + (size_t)b * 4) = ov;
}

extern "C" void kernel_launch(void* const* d_in, const int* in_sizes, int n_in,
                              void* d_out, int out_size, void* d_ws, size_t ws_size,
                              hipStream_t stream) {
    const float* x    = (const float*)d_in[0];
    const float* ew1  = (const float*)d_in[1];
    const float* eb1  = (const float*)d_in[2];
    const float* ew2  = (const float*)d_in[3];
    const float* eb2  = (const float*)d_in[4];
    const float* ew3  = (const float*)d_in[5];
    const float* eb3  = (const float*)d_in[6];
    const float* nw1  = (const float*)d_in[7];
    const float* nb1  = (const float*)d_in[8];
    const float* nw2  = (const float*)d_in[9];
    const float* nb2  = (const float*)d_in[10];
    const float* alog = (const float*)d_in[11];
    const float* rlog = (const float*)d_in[12];
    const float* rw1  = (const float*)d_in[13];
    const float* rb1  = (const float*)d_in[14];
    const float* rw2  = (const float*)d_in[15];
    const float* rb2  = (const float*)d_in[16];
    float* out = (float*)d_out;

    const int B = in_sizes[0] / 60;   // x is (B, 15, 4)
    const size_t ws_needed = (size_t)B * 20 * sizeof(float);

    if (ws_size >= ws_needed) {
        float* ws = (float*)d_ws;
        const int g1 = (B + 255) / 256;
        topo_k1<<<g1, 256, 0, stream>>>(x, ew1, eb1, ew2, eb2, ew3, eb3,
                                        alog, rlog, ws, B);
        const long long tot2 = (long long)B * 4;
        const int g2 = (int)((tot2 + 255) / 256);
        topo_k2<<<g2, 256, 0, stream>>>(ws, nw1, nb1, nw2, nb2,
                                        rw1, rb1, rw2, rb2, out, B);
    } else {
        const int g = (B + 255) / 256;
        topo_fused<<<g, 256, 0, stream>>>(
            x, ew1, eb1, ew2, eb2, ew3, eb3, nw1, nb1, nw2, nb2,
            alog, rlog, rw1, rb1, rw2, rb2, out, B);
    }
}